// Round 12
// baseline (41.833 us; speedup 1.0000x reference)
//
#include <hip/hip_runtime.h>
#include <math.h>

namespace {
constexpr int L = 7, S = 200, SE = 240, D = 32, B = 512;
constexpr int NTOK = L * B;      // 3584
constexpr int NCLUST = L * S;    // 1400
constexpr int GRID1 = 256;       // one block per CU
constexpr int WPB = 8;           // 512 threads = 8 waves per block
constexpr int NWAVE = GRID1 * WPB;        // 2048 waves
constexpr int NTASK = NCLUST + NTOK;      // 4984 wave-tasks (compose first)

// ---- cross-lane helpers: DPP (VALU-speed), DS only for xor16 (proven R8/R9) ----
template <int CTRL>
__device__ __forceinline__ float dppf(float x) {
  return __int_as_float(__builtin_amdgcn_update_dpp(
      0, __float_as_int(x), CTRL, 0xF, 0xF, true));
}
template <int CTRL>
__device__ __forceinline__ int dppi(int x) {
  return __builtin_amdgcn_update_dpp(0, x, CTRL, 0xF, 0xF, true);
}
// quad_perm[1,0,3,2]=0xB1 (xor1), quad_perm[2,3,0,1]=0x4E (xor2),
// row_half_mirror=0x141 (lane^7 in 16 => other quad), row_ror:8=0x128 (lane^8 in 16).
__device__ __forceinline__ float swz16f(float x) {  // lane^16 (within 32)
  return __int_as_float(__builtin_amdgcn_ds_swizzle(__float_as_int(x), 0x401F));
}
__device__ __forceinline__ int swz16i(int x) {
  return __builtin_amdgcn_ds_swizzle(x, 0x401F);
}

// ---------------- node 1: 256 blocks x 8 waves, task-striped wave scheduling ----------------
// Wave W handles tasks {W, W+2048, W+4096} ∩ [0,4984).
// Task t < 1400: compose C[t,:]. Task t >= 1400: route token t-1400 -> (tki,tkp).
// One block per CU -> deterministic balance: every CU runs ~5.47 compose waves +
// ~14 route waves. Compose tasks have the lowest indices so streaming starts at t0.
__global__ __launch_bounds__(512) void fused1_kernel(
    const float* __restrict__ x,     // [L,B,D]
    const float* __restrict__ vc,    // [L,S,D]
    const float* __restrict__ vec,   // [L,S,SE,D]
    const float* __restrict__ gain,  // [L,S,SE,2]
    const int* __restrict__ blk,     // [L,S,SE,2]
    float* __restrict__ C,           // [L*S, D] ws
    int4* __restrict__ tki,          // [NTOK] ws
    float4* __restrict__ tkp)        // [NTOK] ws
{
  const int wave = threadIdx.x >> 6;
  const int lane = threadIdx.x & 63;
  const int W = blockIdx.x * WPB + wave;  // global wave id [0, 2048)
  const int q = lane & 7;   // float4 column [0,8)
  const int r8 = lane >> 3; // octet / row group [0,8)

  __shared__ float sw[WPB][SE];  // per-wave weight slot (in-wave write->read, lgkmcnt)

  for (int t = W; t < NTASK; t += NWAVE) {
    if (t < NCLUST) {
      // ---- compose: this wave owns cluster t ----
      const int ls = t;
      for (int e = lane; e < SE; e += 64) {
        const float2 g2 = reinterpret_cast<const float2*>(gain)[ls * SE + e];  // 8B coalesced
        const int2 b2 = reinterpret_cast<const int2*>(blk)[ls * SE + e];
        sw[wave][e] = (b2.x != 0) ? 1.0f / (1.0f + __expf(-g2.x)) : 0.0f;
      }
      // in-wave LDS write->read: compiler inserts lgkmcnt (R10-validated pattern)
      const float4* v4 = reinterpret_cast<const float4*>(vec) + (size_t)ls * SE * 8;
      float4 acc = make_float4(0.f, 0.f, 0.f, 0.f);
#pragma unroll 10
      for (int k = 0; k < 30; ++k) {  // wave reads 8 rows x 128B = 1KB contiguous per step
        const int e = k * 8 + r8;
        const float we = sw[wave][e];
        const float4 v = v4[e * 8 + q];
        acc.x += we * v.x; acc.y += we * v.y; acc.z += we * v.z; acc.w += we * v.w;
      }
      // reduce over r8 (lane bits 3,4,5): xor8 DPP, xor16 swizzle, xor32 shfl
      acc.x += dppf<0x128>(acc.x); acc.y += dppf<0x128>(acc.y);
      acc.z += dppf<0x128>(acc.z); acc.w += dppf<0x128>(acc.w);
      acc.x += swz16f(acc.x); acc.y += swz16f(acc.y);
      acc.z += swz16f(acc.z); acc.w += swz16f(acc.w);
      acc.x += __shfl_xor(acc.x, 32); acc.y += __shfl_xor(acc.y, 32);
      acc.z += __shfl_xor(acc.z, 32); acc.w += __shfl_xor(acc.w, 32);
      if (r8 == 0) reinterpret_cast<float4*>(C + ls * D)[q] = acc;
    } else {
      // ---- route-A: this wave owns token t-NCLUST (R8/R9-proven DPP path) ----
      const int tok = t - NCLUST;
      const int l = tok >> 9;  // B = 512

      const float4 xq = reinterpret_cast<const float4*>(x + tok * D)[q];  // one 128B line
      const float* vcl = vc + l * S * D;

      float v0 = -INFINITY, v1 = -INFINITY, v2 = -INFINITY;
      int i0 = 0x7fffffff, i1 = 0x7fffffff, i2 = 0x7fffffff;
      for (int s0 = 0; s0 < S; s0 += 8) {  // 25 chunks; 8 rows x 128B contiguous per wave
        const int row = s0 + r8;
        const float4 v = reinterpret_cast<const float4*>(vcl + row * D)[q];
        float part = v.x * xq.x + v.y * xq.y + v.z * xq.z + v.w * xq.w;
        part += dppf<0xB1>(part);   // xor1 (quad_perm)
        part += dppf<0x4E>(part);   // xor2 (quad_perm)
        part += dppf<0x141>(part);  // other quad of octet (quads uniform after xor1/2)
        // all 8 lanes of octet r8 hold the dot for `row`; insert on all lanes
        if (part > v0) { v2 = v1; i2 = i1; v1 = v0; i1 = i0; v0 = part; i0 = row; }
        else if (part > v1) { v2 = v1; i2 = i1; v1 = part; i1 = row; }
        else if (part > v2) { v2 = part; i2 = row; }
      }
      // 3-step merge across octets (partners hold disjoint row residues)
#pragma unroll
      for (int step = 0; step < 3; ++step) {
        float u0, u1, u2; int j0, j1, j2;
        if (step == 0) {
          u0 = dppf<0x128>(v0); u1 = dppf<0x128>(v1); u2 = dppf<0x128>(v2);
          j0 = dppi<0x128>(i0); j1 = dppi<0x128>(i1); j2 = dppi<0x128>(i2);
        } else if (step == 1) {
          u0 = swz16f(v0); u1 = swz16f(v1); u2 = swz16f(v2);
          j0 = swz16i(i0); j1 = swz16i(i1); j2 = swz16i(i2);
        } else {
          u0 = __shfl_xor(v0, 32); u1 = __shfl_xor(v1, 32); u2 = __shfl_xor(v2, 32);
          j0 = __shfl_xor(i0, 32); j1 = __shfl_xor(i1, 32); j2 = __shfl_xor(i2, 32);
        }
#pragma unroll
        for (int tt = 0; tt < 3; ++tt) {  // jax tie-break: desc value, lower index
          const float u = (tt == 0) ? u0 : (tt == 1) ? u1 : u2;
          const int j = (tt == 0) ? j0 : (tt == 1) ? j1 : j2;
          const bool b0 = (u > v0) || (u == v0 && j < i0);
          const bool b1 = (u > v1) || (u == v1 && j < i1);
          const bool b2 = (u > v2) || (u == v2 && j < i2);
          if (b0) { v2 = v1; i2 = i1; v1 = v0; i1 = i0; v0 = u; i0 = j; }
          else if (b1) { v2 = v1; i2 = i1; v1 = u; i1 = j; }
          else if (b2) { v2 = u; i2 = j; }
        }
      }
      if (lane == 0) {
        const float e1 = __expf(v1 - v0);
        const float e2 = __expf(v2 - v0);
        const float inv = 1.f / (1.f + e1 + e2);
        tki[tok] = make_int4(i0, i1, i2, 0);
        tkp[tok] = make_float4(inv, e1 * inv, e2 * inv, 0.f);
      }
    }
  }
}

// ---------------- node 2: gather. Thread per (token, d). ----------------
// tki/tkp uniform per 32-thread token-group -> broadcast loads; C rows 128B
// contiguous, L2-hot (C = 180KB); out fully coalesced.
__global__ __launch_bounds__(256) void gather_kernel(
    const float* __restrict__ C,      // [L*S, D]
    const int4* __restrict__ tki,     // [NTOK]
    const float4* __restrict__ tkp,   // [NTOK]
    float* __restrict__ out)          // [L,B,D]
{
  const int gid = blockIdx.x * 256 + threadIdx.x;  // 448 blocks * 256 = NTOK*D
  const int tok = gid >> 5;
  const int d = gid & 31;
  const int l = tok >> 9;
  const int4 id = tki[tok];
  const float4 p = tkp[tok];
  const float* Cl = C + l * S * D;
  out[gid] = p.x * Cl[id.x * D + d] + p.y * Cl[id.y * D + d] + p.z * Cl[id.z * D + d];
}

}  // namespace

extern "C" void kernel_launch(void* const* d_in, const int* in_sizes, int n_in,
                              void* d_out, int out_size, void* d_ws, size_t ws_size,
                              hipStream_t stream) {
  const float* x = (const float*)d_in[0];      // [L,B,D]
  const float* vc = (const float*)d_in[1];     // [L,S,D]
  const float* vec = (const float*)d_in[2];    // [L,S,SE,D]
  const float* gain = (const float*)d_in[3];   // [L,S,SE,2]
  const int* blk = (const int*)d_in[4];        // [L,S,SE,2]
  float* out = (float*)d_out;                  // [L,B,D]

  char* ws = (char*)d_ws;
  float* C = (float*)ws;                          // 179,200 B
  int4* tki = (int4*)(ws + 179200);               // 57,344 B (16B aligned)
  float4* tkp = (float4*)(ws + 179200 + 57344);   // 57,344 B

  fused1_kernel<<<GRID1, 512, 0, stream>>>(x, vc, vec, gain, blk, C, tki, tkp);
  gather_kernel<<<NTOK * D / 256, 256, 0, stream>>>(C, tki, tkp, out);
}

// Round 13
// 24.293 us; speedup vs baseline: 1.7220x; 1.7220x over previous
//
#include <hip/hip_runtime.h>
#include <math.h>

namespace {
constexpr int L = 7, S = 200, SE = 240, D = 32, B = 512;
constexpr int NTOK = L * B;      // 3584
constexpr int NCLUST = L * S;    // 1400
constexpr int NSLOT = NCLUST + NTOK;   // 4984 wave-slots
constexpr int GRID1 = NSLOT / 4;       // 1246 blocks x 4 waves (R9's proven shape)

// ---- cross-lane helpers: DPP (VALU-speed), DS only for xor16 (proven R8/R9) ----
template <int CTRL>
__device__ __forceinline__ float dppf(float x) {
  return __int_as_float(__builtin_amdgcn_update_dpp(
      0, __float_as_int(x), CTRL, 0xF, 0xF, true));
}
template <int CTRL>
__device__ __forceinline__ int dppi(int x) {
  return __builtin_amdgcn_update_dpp(0, x, CTRL, 0xF, 0xF, true);
}
// quad_perm[1,0,3,2]=0xB1 (xor1), quad_perm[2,3,0,1]=0x4E (xor2),
// row_half_mirror=0x141 (lane^7 in 16 => other quad), row_ror:8=0x128 (lane^8 in 16).
__device__ __forceinline__ float swz16f(float x) {  // lane^16 (within 32)
  return __int_as_float(__builtin_amdgcn_ds_swizzle(__float_as_int(x), 0x401F));
}
__device__ __forceinline__ int swz16i(int x) {
  return __builtin_amdgcn_ds_swizzle(x, 0x401F);
}

// ---------------- node 1: compose || route, balanced task spread ----------------
// Wave-slot s in [0,4984). Compose slots are spread evenly (every ~3.56th slot)
// via the floor-ratio trick, so every CU's ~19.5 slots carry 5-6 compose clusters
// (R9 packed compose into blocks 0-349: CUs 0-93 carried 8, rest 4 -> 1.5x tail).
//   nc(s) = floor(s*1400/4984); compose slot iff nc(s+1) > nc(s);
//   compose_id = nc(s) in [0,1400); route_id = s - nc(s) in [0,3584).
__global__ __launch_bounds__(256) void fused1_kernel(
    const float* __restrict__ x,     // [L,B,D]
    const float* __restrict__ vc,    // [L,S,D]
    const float* __restrict__ vec,   // [L,S,SE,D]
    const float* __restrict__ gain,  // [L,S,SE,2]
    const int* __restrict__ blk,     // [L,S,SE,2]
    float* __restrict__ C,           // [L*S, D] ws
    int4* __restrict__ tki,          // [NTOK] ws
    float4* __restrict__ tkp)        // [NTOK] ws
{
  const int wave = threadIdx.x >> 6;
  const int lane = threadIdx.x & 63;
  const int s = blockIdx.x * 4 + wave;  // wave-slot [0, 4984)
  const int q = lane & 7;   // float4 column [0,8)
  const int r8 = lane >> 3; // octet / row group [0,8)

  const int nc0 = (s * NCLUST) / NSLOT;        // compose slots before s
  const int nc1 = ((s + 1) * NCLUST) / NSLOT;  // ... and including s

  if (nc1 > nc0) {
    // ---- compose: this wave owns cluster nc0 ----
    const int ls = nc0;
    __shared__ float sw[4][SE];
    for (int e = lane; e < SE; e += 64) {
      const float2 g2 = reinterpret_cast<const float2*>(gain)[ls * SE + e];  // 8B coalesced
      const int2 b2 = reinterpret_cast<const int2*>(blk)[ls * SE + e];
      sw[wave][e] = (b2.x != 0) ? 1.0f / (1.0f + __expf(-g2.x)) : 0.0f;
    }
    // in-wave LDS write->read: compiler inserts lgkmcnt (R10/R12-validated pattern)
    const float4* v4 = reinterpret_cast<const float4*>(vec) + (size_t)ls * SE * 8;
    float4 acc = make_float4(0.f, 0.f, 0.f, 0.f);
#pragma unroll 10
    for (int k = 0; k < 30; ++k) {  // wave reads 8 rows x 128B = 1KB contiguous per step
      const int e = k * 8 + r8;
      const float we = sw[wave][e];
      const float4 v = v4[e * 8 + q];
      acc.x += we * v.x; acc.y += we * v.y; acc.z += we * v.z; acc.w += we * v.w;
    }
    // reduce over r8 (lane bits 3,4,5): xor8 DPP, xor16 swizzle, xor32 shfl
    acc.x += dppf<0x128>(acc.x); acc.y += dppf<0x128>(acc.y);
    acc.z += dppf<0x128>(acc.z); acc.w += dppf<0x128>(acc.w);
    acc.x += swz16f(acc.x); acc.y += swz16f(acc.y);
    acc.z += swz16f(acc.z); acc.w += swz16f(acc.w);
    acc.x += __shfl_xor(acc.x, 32); acc.y += __shfl_xor(acc.y, 32);
    acc.z += __shfl_xor(acc.z, 32); acc.w += __shfl_xor(acc.w, 32);
    if (r8 == 0) reinterpret_cast<float4*>(C + ls * D)[q] = acc;
  } else {
    // ---- route-A: this wave owns token s - nc0 (R8/R9-proven DPP path) ----
    const int tok = s - nc0;
    const int l = tok >> 9;  // B = 512

    const float4 xq = reinterpret_cast<const float4*>(x + tok * D)[q];  // one 128B line
    const float* vcl = vc + l * S * D;

    float v0 = -INFINITY, v1 = -INFINITY, v2 = -INFINITY;
    int i0 = 0x7fffffff, i1 = 0x7fffffff, i2 = 0x7fffffff;
    for (int s0 = 0; s0 < S; s0 += 8) {  // 25 chunks; 8 rows x 128B contiguous per wave
      const int row = s0 + r8;
      const float4 v = reinterpret_cast<const float4*>(vcl + row * D)[q];
      float part = v.x * xq.x + v.y * xq.y + v.z * xq.z + v.w * xq.w;
      part += dppf<0xB1>(part);   // xor1 (quad_perm)
      part += dppf<0x4E>(part);   // xor2 (quad_perm)
      part += dppf<0x141>(part);  // other quad of octet (quads uniform after xor1/2)
      // all 8 lanes of octet r8 hold the dot for `row`; insert on all lanes
      if (part > v0) { v2 = v1; i2 = i1; v1 = v0; i1 = i0; v0 = part; i0 = row; }
      else if (part > v1) { v2 = v1; i2 = i1; v1 = part; i1 = row; }
      else if (part > v2) { v2 = part; i2 = row; }
    }
    // 3-step merge across octets (partners hold disjoint row residues)
#pragma unroll
    for (int step = 0; step < 3; ++step) {
      float u0, u1, u2; int j0, j1, j2;
      if (step == 0) {
        u0 = dppf<0x128>(v0); u1 = dppf<0x128>(v1); u2 = dppf<0x128>(v2);
        j0 = dppi<0x128>(i0); j1 = dppi<0x128>(i1); j2 = dppi<0x128>(i2);
      } else if (step == 1) {
        u0 = swz16f(v0); u1 = swz16f(v1); u2 = swz16f(v2);
        j0 = swz16i(i0); j1 = swz16i(i1); j2 = swz16i(i2);
      } else {
        u0 = __shfl_xor(v0, 32); u1 = __shfl_xor(v1, 32); u2 = __shfl_xor(v2, 32);
        j0 = __shfl_xor(i0, 32); j1 = __shfl_xor(i1, 32); j2 = __shfl_xor(i2, 32);
      }
#pragma unroll
      for (int t = 0; t < 3; ++t) {  // jax tie-break: desc value, lower index
        const float u = (t == 0) ? u0 : (t == 1) ? u1 : u2;
        const int j = (t == 0) ? j0 : (t == 1) ? j1 : j2;
        const bool b0 = (u > v0) || (u == v0 && j < i0);
        const bool b1 = (u > v1) || (u == v1 && j < i1);
        const bool b2 = (u > v2) || (u == v2 && j < i2);
        if (b0) { v2 = v1; i2 = i1; v1 = v0; i1 = i0; v0 = u; i0 = j; }
        else if (b1) { v2 = v1; i2 = i1; v1 = u; i1 = j; }
        else if (b2) { v2 = u; i2 = j; }
      }
    }
    if (lane == 0) {
      const float e1 = __expf(v1 - v0);
      const float e2 = __expf(v2 - v0);
      const float inv = 1.f / (1.f + e1 + e2);
      tki[tok] = make_int4(i0, i1, i2, 0);
      tkp[tok] = make_float4(inv, e1 * inv, e2 * inv, 0.f);
    }
  }
}

// ---------------- node 2: gather. Thread per (token, d). ----------------
// tki/tkp uniform per 32-thread token-group -> broadcast loads; C rows 128B
// contiguous, L2-hot (C = 180KB); out fully coalesced.
__global__ __launch_bounds__(256) void gather_kernel(
    const float* __restrict__ C,      // [L*S, D]
    const int4* __restrict__ tki,     // [NTOK]
    const float4* __restrict__ tkp,   // [NTOK]
    float* __restrict__ out)          // [L,B,D]
{
  const int gid = blockIdx.x * 256 + threadIdx.x;  // 448 blocks * 256 = NTOK*D
  const int tok = gid >> 5;
  const int d = gid & 31;
  const int l = tok >> 9;
  const int4 id = tki[tok];
  const float4 p = tkp[tok];
  const float* Cl = C + l * S * D;
  out[gid] = p.x * Cl[id.x * D + d] + p.y * Cl[id.y * D + d] + p.z * Cl[id.z * D + d];
}

}  // namespace

extern "C" void kernel_launch(void* const* d_in, const int* in_sizes, int n_in,
                              void* d_out, int out_size, void* d_ws, size_t ws_size,
                              hipStream_t stream) {
  const float* x = (const float*)d_in[0];      // [L,B,D]
  const float* vc = (const float*)d_in[1];     // [L,S,D]
  const float* vec = (const float*)d_in[2];    // [L,S,SE,D]
  const float* gain = (const float*)d_in[3];   // [L,S,SE,2]
  const int* blk = (const int*)d_in[4];        // [L,S,SE,2]
  float* out = (float*)d_out;                  // [L,B,D]

  char* ws = (char*)d_ws;
  float* C = (float*)ws;                          // 179,200 B
  int4* tki = (int4*)(ws + 179200);               // 57,344 B (16B aligned)
  float4* tkp = (float4*)(ws + 179200 + 57344);   // 57,344 B

  fused1_kernel<<<GRID1, 256, 0, stream>>>(x, vc, vec, gain, blk, C, tki, tkp);
  gather_kernel<<<NTOK * D / 256, 256, 0, stream>>>(C, tki, tkp, out);
}